// Round 2
// baseline (317.743 us; speedup 1.0000x reference)
//
#include <hip/hip_runtime.h>
#include <hip/hip_bf16.h>
#include <hip/hip_cooperative_groups.h>

namespace cg = cooperative_groups;

#define Hh 96
#define Ww 128
#define Cc 21
#define Nn (Hh * Ww)      // 12288
#define RAD 20            // exp(-d^2/18) < 3e-10 beyond d=20

// One cooperative kernel: precompute + transpose + 5 CRF iterations.
// 128 blocks x 256 threads (1 block/CU on 256 CUs -> trivially co-resident).
// Row phase (blocks 0..95): softmax over classes + horizontal blur -> t.
// Col phase (blocks 0..127): vertical blur + normalize + M-mix + q update.
__global__ __launch_bounds__(256) void crf_fused_k(
    const float* __restrict__ u, const float* __restrict__ Ws,
    const float* __restrict__ Wb, const float* __restrict__ compat,
    float* __restrict__ outp, float* __restrict__ u_t,
    float* __restrict__ q, float* __restrict__ t) {
  cg::grid_group grid = cg::this_grid();
  const int bid = blockIdx.x;
  const int tid = threadIdx.x;

  __shared__ float M_ld[Cc * Cc];
  __shared__ float ny_ld[Hh];
  // union buffer: row phase p_pad[21*168]=3528; col phase t_pad[21*136]=2856
  // followed by s_ld[21*96]=2016 (2856+2016=4872 floats = 19.5 KB)
  __shared__ __align__(16) float buf[4872];

  float w[RAD + 1];
  #pragma unroll
  for (int d = 0; d <= RAD; ++d)
    w[d] = __expf((float)(d * d) * (-1.f / 18.f));

  // ---- per-block precompute (redundant, ~9k FMA: free) ----
  for (int i = tid; i < Cc * Cc; i += 256) {
    int a = i / Cc, b = i % Cc;
    float acc = 0.f;
    #pragma unroll
    for (int k = 0; k < Cc; ++k)
      acc += compat[a * Cc + k] * (Ws[k * Cc + b] + Wb[k * Cc + b]);
    M_ld[i] = acc;
  }
  if (tid < Hh) {
    float s = 0.f;
    for (int yp = 0; yp < Hh; ++yp) {
      float d = (float)(tid - yp);
      s += __expf(d * d * (-1.f / 18.f));
    }
    ny_ld[tid] = s;
  }
  float nxv = 0.f;  // norm factor for this block's column (col phase: x = bid)
  for (int xp = 0; xp < Ww; ++xp) {
    float d = (float)(bid - xp);
    nxv += __expf(d * d * (-1.f / 18.f));
  }

  // ---- transpose u (NHWC) -> u_t [C][N] ----
  {
    int n = bid * 256 + tid;  // 32768 threads >= 12288 pixels
    if (n < Nn) {
      #pragma unroll
      for (int c = 0; c < Cc; ++c) u_t[c * Nn + n] = u[n * Cc + c];
    }
  }
  grid.sync();

  for (int it = 0; it < 5; ++it) {
    const float* qin = (it == 0) ? u_t : q;

    // ================= row phase: softmax + horizontal blur =================
    if (bid < Hh) {
      const int h = bid;
      float* p_pad = buf;  // [21][168]: 20 guard | 128 data | 20 guard
      for (int i = tid; i < Cc * 2 * RAD; i += 256) {
        int r = i / (2 * RAD), g = i % (2 * RAD);
        p_pad[r * 168 + (g < RAD ? g : (Ww + g))] = 0.f;
      }
      if (tid < Ww) {
        float v[Cc];
        float m = -1e30f;
        #pragma unroll
        for (int c = 0; c < Cc; ++c) {
          v[c] = qin[c * Nn + h * Ww + tid];
          m = fmaxf(m, v[c]);
        }
        float s = 0.f;
        #pragma unroll
        for (int c = 0; c < Cc; ++c) { v[c] = __expf(v[c] - m); s += v[c]; }
        float inv = 1.f / s;
        #pragma unroll
        for (int c = 0; c < Cc; ++c) p_pad[c * 168 + RAD + tid] = v[c] * inv;
      }
      __syncthreads();

      // blur: 21 channels x 32 quads of x (4 outputs/task)
      for (int i = tid; i < Cc * 32; i += 256) {
        int c = i >> 5, xq = i & 31;
        int x0 = xq * 4;
        const float* row = &p_pad[c * 168];
        float acc[4] = {0.f, 0.f, 0.f, 0.f};
        #pragma unroll
        for (int j = 0; j < 11; ++j) {
          float4 pv4 = *(const float4*)&row[x0 + 4 * j];
          float pv[4] = {pv4.x, pv4.y, pv4.z, pv4.w};
          #pragma unroll
          for (int k = 0; k < 4; ++k) {
            #pragma unroll
            for (int o = 0; o < 4; ++o) {
              int d = 4 * j + k - RAD - o;  // compile-time after unroll
              int ad = d < 0 ? -d : d;
              if (ad <= RAD) acc[o] += w[ad] * pv[k];
            }
          }
        }
        float4 res = {acc[0], acc[1], acc[2], acc[3]};
        *(float4*)&t[c * Nn + h * Ww + x0] = res;
      }
    }
    grid.sync();

    // ====== col phase: vertical blur + normalize + M-mix + q update ======
    {
      const int x = bid;
      float* t_pad = buf;          // [21][136]: 20 | 96 | 20
      float* s_ld = buf + Cc * 136;  // [21][96]
      for (int i = tid; i < Cc * 2 * RAD; i += 256) {
        int r = i / (2 * RAD), g = i % (2 * RAD);
        t_pad[r * 136 + (g < RAD ? g : (Hh + g))] = 0.f;
      }
      for (int i = tid; i < Cc * Hh; i += 256) {
        int c = i / Hh, hh = i % Hh;
        t_pad[c * 136 + RAD + hh] = t[c * Nn + hh * Ww + x];
      }
      __syncthreads();

      for (int i = tid; i < Cc * 24; i += 256) {
        int c = i / 24, hq = i % 24;
        int h0 = hq * 4;
        const float* col = &t_pad[c * 136];
        float acc[4] = {0.f, 0.f, 0.f, 0.f};
        #pragma unroll
        for (int j = 0; j < 11; ++j) {
          float4 tv4 = *(const float4*)&col[h0 + 4 * j];
          float tv[4] = {tv4.x, tv4.y, tv4.z, tv4.w};
          #pragma unroll
          for (int k = 0; k < 4; ++k) {
            #pragma unroll
            for (int o = 0; o < 4; ++o) {
              int d = 4 * j + k - RAD - o;
              int ad = d < 0 ? -d : d;
              if (ad <= RAD) acc[o] += w[ad] * tv[k];
            }
          }
        }
        #pragma unroll
        for (int o = 0; o < 4; ++o)
          s_ld[c * 96 + h0 + o] = acc[o] / (nxv * ny_ld[h0 + o]);
      }
      __syncthreads();

      for (int i = tid; i < Cc * 24; i += 256) {
        int c = i / 24, hq = i % 24;
        int h0 = hq * 4;
        float acc[4] = {0.f, 0.f, 0.f, 0.f};
        #pragma unroll
        for (int b = 0; b < Cc; ++b) {
          float m = M_ld[c * Cc + b];
          float4 sv = *(const float4*)&s_ld[b * 96 + h0];
          acc[0] += m * sv.x;
          acc[1] += m * sv.y;
          acc[2] += m * sv.z;
          acc[3] += m * sv.w;
        }
        #pragma unroll
        for (int o = 0; o < 4; ++o) {
          int hh = h0 + o;
          float qn = u_t[c * Nn + hh * Ww + x] - acc[o];
          if (it == 4) outp[(x * Hh + hh) * Cc + c] = qn;  // out[0][w][h][c]
          else q[c * Nn + hh * Ww + x] = qn;
        }
      }
    }
    grid.sync();
  }
}

// ---------------------------------------------------------------------------
extern "C" void kernel_launch(void* const* d_in, const int* in_sizes, int n_in,
                              void* d_out, int out_size, void* d_ws, size_t ws_size,
                              hipStream_t stream) {
  const float* u      = (const float*)d_in[0];  // (1,H,W,C)
  // d_in[1] = rgb: DEAD (replicated source bug uses spatial_out twice)
  const float* Ws     = (const float*)d_in[2];
  const float* Wb     = (const float*)d_in[3];
  const float* compat = (const float*)d_in[4];
  float* out = (float*)d_out;

  float* ws  = (float*)d_ws;
  float* u_t = ws;             // [C][N] 258048 floats
  float* q   = ws + 258048;    // [C][N]
  float* t   = ws + 516096;    // [C][N]

  void* args[] = {(void*)&u, (void*)&Ws, (void*)&Wb, (void*)&compat,
                  (void*)&out, (void*)&u_t, (void*)&q, (void*)&t};
  hipLaunchCooperativeKernel((void*)crf_fused_k, dim3(128), dim3(256),
                             args, 0, stream);
}

// Round 3
// 190.023 us; speedup vs baseline: 1.6721x; 1.6721x over previous
//
#include <hip/hip_runtime.h>
#include <hip/hip_bf16.h>

#define Hh 96
#define Ww 128
#define Cc 21
#define Nn (Hh * Ww)     // 12288
#define RAD 20           // exp(-d^2/18) < 3e-10 beyond d=20
#define WIN (2 * RAD + 1)  // 41
#define APAD 137         // padded column stride (137%32=9 -> conflict-free)
#define SPAD 97          // padded stride for s (97%32=1)

// One kernel per CRF iteration. Block = one image column x (128 blocks).
// Phase A: threads (p<2, h) redundantly compute softmax over the 41-column
//          halo window and H-blur-accumulate into registers (no races, no
//          syncs), then dump to LDS.
// Phase B: vertical blur + exact nx*ny normalization (norm_s separates).
// Phase C: q_new = u - M @ s, M = compat @ (Ws+Wb)  (bilateral term is dead
//          code in the reference: message uses spatial_out twice).
// q layout [x][h][c] == output layout (1,W,H,C): last iter writes d_out.
__global__ __launch_bounds__(256) void crf_iter_k(
    const float* __restrict__ qin, int sxs, int sh,
    const float* __restrict__ u,
    const float* __restrict__ Ws, const float* __restrict__ Wb,
    const float* __restrict__ compat,
    float* __restrict__ qout) {
  const int x = blockIdx.x;
  const int tid = threadIdx.x;

  __shared__ float M_ld[Cc * Cc];
  __shared__ float ny_ld[Hh];
  __shared__ float w_ld[RAD + 1];
  __shared__ __align__(16) float acc[2 * Cc * APAD];  // two parity accumulators
  __shared__ __align__(16) float s_ld[Cc * SPAD];

  // ---- per-block precompute (cheap, redundant across blocks) ----
  if (tid <= RAD) w_ld[tid] = __expf((float)(tid * tid) * (-1.f / 18.f));
  for (int i = tid; i < Cc * Cc; i += 256) {
    int a = i / Cc, b = i % Cc;
    float s = 0.f;
    #pragma unroll
    for (int k = 0; k < Cc; ++k)
      s += compat[a * Cc + k] * (Ws[k * Cc + b] + Wb[k * Cc + b]);
    M_ld[i] = s;
  }
  if (tid < Hh) {
    float s = 0.f;
    for (int yp = 0; yp < Hh; ++yp) {
      float d = (float)(tid - yp);
      s += __expf(d * d * (-1.f / 18.f));
    }
    ny_ld[tid] = s;
  }
  float nxv = 0.f;  // full-width norm factor for column x (exact)
  for (int xp = 0; xp < Ww; ++xp) {
    float d = (float)(x - xp);
    nxv += __expf(d * d * (-1.f / 18.f));
  }
  for (int i = tid; i < 2 * Cc * APAD; i += 256) acc[i] = 0.f;
  __syncthreads();

  // ---- Phase A: softmax + horizontal blur (register accumulation) ----
  {
    const int p = tid / Hh;  // 0 or 1 active; tid>=192 idle here
    const int h = tid % Hh;
    if (p < 2) {
      float tacc[Cc];
      #pragma unroll
      for (int c = 0; c < Cc; ++c) tacc[c] = 0.f;
      for (int g = 0; g < WIN; g += 2) {
        int off = g + p;
        if (off >= WIN) break;         // only p=1's last step
        int xs = x - RAD + off;
        if (xs < 0 || xs >= Ww) continue;
        const float* src = qin + (size_t)xs * sxs + (size_t)h * sh;
        float v[Cc];
        float m = -1e30f;
        #pragma unroll
        for (int c = 0; c < Cc; ++c) { v[c] = src[c]; m = fmaxf(m, v[c]); }
        float ssum = 0.f;
        #pragma unroll
        for (int c = 0; c < Cc; ++c) { v[c] = __expf(v[c] - m); ssum += v[c]; }
        int ad = off - RAD; if (ad < 0) ad = -ad;
        float wgt = w_ld[ad] / ssum;   // fold softmax normalizer into weight
        #pragma unroll
        for (int c = 0; c < Cc; ++c) tacc[c] += wgt * v[c];
      }
      float* a = acc + p * (Cc * APAD);
      #pragma unroll
      for (int c = 0; c < Cc; ++c) a[c * APAD + RAD + h] = tacc[c];
    }
  }
  __syncthreads();

  // merge parity-1 accumulator into parity-0 (guards stay zero)
  for (int i = tid; i < Cc * Hh; i += 256) {
    int c = i / Hh, hh = i % Hh;
    int idx = c * APAD + RAD + hh;
    acc[idx] += acc[Cc * APAD + idx];
  }
  __syncthreads();

  // ---- Phase B: vertical blur + normalize ----
  for (int i = tid; i < Cc * Hh; i += 256) {
    int c = i % Cc, hh = i / Cc;
    const float* col = acc + c * APAD + RAD + hh;  // zero guards handle edges
    float sacc = 0.f;
    #pragma unroll
    for (int d = -RAD; d <= RAD; ++d) {
      int ad = d < 0 ? -d : d;
      sacc += w_ld[ad] * col[d];
    }
    s_ld[c * SPAD + hh] = sacc / (nxv * ny_ld[hh]);
  }
  __syncthreads();

  // ---- Phase C: q_new = u - M @ s ; coalesced write in [x][h][c] ----
  for (int i = tid; i < Cc * Hh; i += 256) {
    int c = i % Cc, hh = i / Cc;
    float accv = 0.f;
    #pragma unroll
    for (int b = 0; b < Cc; ++b) accv += M_ld[c * Cc + b] * s_ld[b * SPAD + hh];
    float un = u[((size_t)hh * Ww + x) * Cc + c];
    qout[((size_t)x * Hh + hh) * Cc + c] = un - accv;
  }
}

// ---------------------------------------------------------------------------
extern "C" void kernel_launch(void* const* d_in, const int* in_sizes, int n_in,
                              void* d_out, int out_size, void* d_ws, size_t ws_size,
                              hipStream_t stream) {
  const float* u      = (const float*)d_in[0];  // (1,H,W,C)
  // d_in[1] = rgb: DEAD (replicated source bug uses spatial_out twice)
  const float* Ws     = (const float*)d_in[2];
  const float* Wb     = (const float*)d_in[3];
  const float* compat = (const float*)d_in[4];
  float* out = (float*)d_out;

  float* qa = (float*)d_ws;       // [W][H][C]
  float* qb = qa + Cc * Nn;

  // iter 0 reads u in NHWC: xs-stride=Cc, h-stride=Ww*Cc
  // iters 1..4 read q in [x][h][c]: xs-stride=Hh*Cc, h-stride=Cc
  crf_iter_k<<<Ww, 256, 0, stream>>>(u,  Cc,      Ww * Cc, u, Ws, Wb, compat, qa);
  crf_iter_k<<<Ww, 256, 0, stream>>>(qa, Hh * Cc, Cc,      u, Ws, Wb, compat, qb);
  crf_iter_k<<<Ww, 256, 0, stream>>>(qb, Hh * Cc, Cc,      u, Ws, Wb, compat, qa);
  crf_iter_k<<<Ww, 256, 0, stream>>>(qa, Hh * Cc, Cc,      u, Ws, Wb, compat, qb);
  crf_iter_k<<<Ww, 256, 0, stream>>>(qb, Hh * Cc, Cc,      u, Ws, Wb, compat, out);
}